// Round 2
// baseline (282.591 us; speedup 1.0000x reference)
//
#include <hip/hip_runtime.h>
#include <math.h>

#define NBINS 256
#define NCOPY 16   // LDS sub-histogram copies; copy index = lane & 15

// Fused histogram for both inputs. torch.histc semantics over [-1,1], 256 bins.
// Binning in f32 exactly as the reference: floor((x+1) * 128), clip to 255,
// ignore out-of-range. (width = 2/256 is a power of two, so /width == *128
// with identical rounding.)

__device__ __forceinline__ void proc4(float4 v, unsigned int* __restrict__ lh, int c) {
    float vv[4] = {v.x, v.y, v.z, v.w};
#pragma unroll
    for (int j = 0; j < 4; j++) {
        float f = vv[j];
        if (f >= -1.0f && f <= 1.0f) {
            // f+1 >= 0 exactly, so trunc == floor; value 256 only at f==1.0
            int bin = (int)((f + 1.0f) * 128.0f);
            bin = bin > (NBINS - 1) ? (NBINS - 1) : bin;
            atomicAdd(&lh[(bin << 4) + c], 1u);
        }
    }
}

__global__ __launch_bounds__(256) void hist2_kernel(const float* __restrict__ a,
                                                    const float* __restrict__ b,
                                                    unsigned int* __restrict__ ghist,
                                                    int n4a, int n4b, int half_blocks) {
    __shared__ unsigned int lh[NBINS * NCOPY];  // 16 KB
    const int tid = threadIdx.x;
    for (int i = tid; i < NBINS * NCOPY; i += 256) lh[i] = 0u;
    __syncthreads();

    const int which = (blockIdx.x >= half_blocks) ? 1 : 0;
    const float4* __restrict__ x4 = (const float4*)(which ? b : a);
    const int n4 = which ? n4b : n4a;
    const int bid = which ? (blockIdx.x - half_blocks) : blockIdx.x;
    const int c = tid & (NCOPY - 1);
    const int stride = half_blocks * 256;

    // 4x-unrolled grid-stride loop: issue 4 independent coalesced float4
    // loads back-to-back so each wave keeps ~4-5 VMEM ops in flight
    // (latency-bound fix; each load instruction is still lane-contiguous).
    int i = bid * 256 + tid;
    for (; i + 3 * stride < n4; i += 4 * stride) {
        float4 v0 = x4[i];
        float4 v1 = x4[i + stride];
        float4 v2 = x4[i + 2 * stride];
        float4 v3 = x4[i + 3 * stride];
        proc4(v0, lh, c);
        proc4(v1, lh, c);
        proc4(v2, lh, c);
        proc4(v3, lh, c);
    }
    for (; i < n4; i += stride) {
        proc4(x4[i], lh, c);
    }
    __syncthreads();

    // Fold 16 copies; one bin per thread (blockDim == NBINS)
    unsigned int s = 0;
#pragma unroll
    for (int k = 0; k < NCOPY; k++) s += lh[(tid << 4) + k];
    atomicAdd(&ghist[which * NBINS + tid], s);
}

// Entropy of both histograms + |diff|, all in double. One block of 256 threads.
__global__ __launch_bounds__(256) void entropy_kernel(const unsigned int* __restrict__ gh,
                                                      float* __restrict__ out) {
    __shared__ double sd[NBINS];
    const int tid = threadIdx.x;
    double e[2];

    for (int h = 0; h < 2; h++) {
        const double hv = (double)gh[h * NBINS + tid];

        sd[tid] = hv;
        __syncthreads();
        for (int o = 128; o > 0; o >>= 1) {
            if (tid < o) sd[tid] += sd[tid + o];
            __syncthreads();
        }
        const double total = sd[0];
        __syncthreads();

        const double p = hv / total + 1e-8;
        sd[tid] = -p * log(p);
        __syncthreads();
        for (int o = 128; o > 0; o >>= 1) {
            if (tid < o) sd[tid] += sd[tid + o];
            __syncthreads();
        }
        e[h] = sd[0];
        __syncthreads();
    }

    if (tid == 0) out[0] = (float)fabs(e[0] - e[1]);
}

extern "C" void kernel_launch(void* const* d_in, const int* in_sizes, int n_in,
                              void* d_out, int out_size, void* d_ws, size_t ws_size,
                              hipStream_t stream) {
    const float* pred = (const float*)d_in[0];
    const float* gt   = (const float*)d_in[1];
    const int n0 = in_sizes[0];
    const int n1 = in_sizes[1];

    unsigned int* hist = (unsigned int*)d_ws;  // [2][NBINS]
    hipMemsetAsync(d_ws, 0, 2 * NBINS * sizeof(unsigned int), stream);

    // 1024 blocks per input = 8 blocks/CU total; 16 KB LDS each -> full occupancy
    const int half_blocks = 1024;
    hist2_kernel<<<2 * half_blocks, 256, 0, stream>>>(pred, gt, hist,
                                                      n0 / 4, n1 / 4, half_blocks);
    entropy_kernel<<<1, 256, 0, stream>>>(hist, (float*)d_out);
}